// Round 7
// baseline (658.596 us; speedup 1.0000x reference)
//
#include <hip/hip_runtime.h>
#include <hip/hip_bf16.h>
#include <stdint.h>
#include <stddef.h>

#define NN 8192
#define DD 128
#define PADW 136  // LDS sim row stride (bf16): breaks power-of-2 bank conflicts

typedef __attribute__((ext_vector_type(8))) short bf16x8;
typedef __attribute__((ext_vector_type(4))) short bf16x4;
typedef __attribute__((ext_vector_type(4))) float f32x4;

static __device__ __forceinline__ unsigned short f2bf(float x) {
  __hip_bfloat16 h = __float2bfloat16(x);
  return *(unsigned short*)&h;
}
static __device__ __forceinline__ float bf2f(short u) {
  return __uint_as_float(((unsigned int)(unsigned short)u) << 16);
}

// ---------------------------------------------------------------------------
// Kernel 1: row-normalize features (fp32) and cast to bf16. One wave per row.
// ---------------------------------------------------------------------------
__global__ __launch_bounds__(256) void normalize_kernel(
    const float* __restrict__ f, __hip_bfloat16* __restrict__ fn) {
  const int wave = threadIdx.x >> 6;
  const int lane = threadIdx.x & 63;
  const int row = blockIdx.x * 4 + wave;
  const float2 v = ((const float2*)(f + (size_t)row * DD))[lane];
  float ss = v.x * v.x + v.y * v.y;
#pragma unroll
  for (int m = 1; m < 64; m <<= 1) ss += __shfl_xor(ss, m, 64);
  const float inv = 1.0f / fmaxf(sqrtf(ss), 1e-8f);
  __hip_bfloat162 o;
  o.x = __float2bfloat16(v.x * inv);
  o.y = __float2bfloat16(v.y * inv);
  ((__hip_bfloat162*)(fn + (size_t)row * DD))[lane] = o;
}

// ---------------------------------------------------------------------------
// Kernel 2a: one 128x128 sim tile: bf16 MFMA GEMM (operand-swapped, fragments
// straight from L2 -- fn is 2 MB), exp -> LDS bf16, then coalesced stores of
// the exp tile to the global sim buffer. (R3-validated; not the bottleneck.)
// ---------------------------------------------------------------------------
__global__ __launch_bounds__(256, 4) void sim_tile_kernel(
    const __hip_bfloat16* __restrict__ fn, __hip_bfloat16* __restrict__ simg,
    int passJ0, int span) {
  __shared__ __hip_bfloat16 simt[128 * PADW];  // 34 KB

  const int tid = threadIdx.x;
  const int lane = tid & 63;
  const int quad = lane >> 4;
  const int l16 = lane & 15;
  const int wx = (tid >> 6) & 1;
  const int wy = tid >> 7;

  const int I0 = blockIdx.y * 128 + wy * 64;
  const int J0 = passJ0 + blockIdx.x * 128 + wx * 64;  // global col

  // GEMM: swapped operands => i = I0+mt*16+l16, j = J0+nt*16+quad*4+r
  f32x4 acc[4][4] = {};
#pragma unroll
  for (int kt = 0; kt < 4; ++kt) {
    const int ko = kt * 32 + quad * 8;
    bf16x8 aF[4], bF[4];
#pragma unroll
    for (int mt = 0; mt < 4; ++mt)
      aF[mt] = *(const bf16x8*)(fn + (size_t)(I0 + mt * 16 + l16) * DD + ko);
#pragma unroll
    for (int nt = 0; nt < 4; ++nt)
      bF[nt] = *(const bf16x8*)(fn + (size_t)(J0 + nt * 16 + l16) * DD + ko);
#pragma unroll
    for (int mt = 0; mt < 4; ++mt)
#pragma unroll
      for (int nt = 0; nt < 4; ++nt)
        acc[mt][nt] = __builtin_amdgcn_mfma_f32_16x16x32_bf16(
            bF[nt], aF[mt], acc[mt][nt], 0, 0, 0);  // SWAPPED
  }

  // exp(sim/T) -> LDS (bf16)
  const float tinv = 1.0f / 0.07f;
#pragma unroll
  for (int mt = 0; mt < 4; ++mt) {
    const int iLoc = wy * 64 + mt * 16 + l16;
#pragma unroll
    for (int nt = 0; nt < 4; ++nt) {
      const int jLoc = wx * 64 + nt * 16 + quad * 4;
      ushort4 w;
      w.x = f2bf(__expf(acc[mt][nt][0] * tinv));
      w.y = f2bf(__expf(acc[mt][nt][1] * tinv));
      w.z = f2bf(__expf(acc[mt][nt][2] * tinv));
      w.w = f2bf(__expf(acc[mt][nt][3] * tinv));
      *(ushort4*)(simt + iLoc * PADW + jLoc) = w;
    }
  }
  __syncthreads();

  // coalesced store: 16 threads x 16 B per row, 16 rows per pass, 8 passes
  const int r0 = tid >> 4;
  const int c = (tid & 15) * 8;
#pragma unroll
  for (int ps = 0; ps < 8; ++ps) {
    const int r = ps * 16 + r0;
    const bf16x8 v = *(const bf16x8*)(simt + r * PADW + c);
    *(bf16x8*)(simg + (size_t)(blockIdx.y * 128 + r) * span +
               blockIdx.x * 128 + c) = v;
  }
}

// ---------------------------------------------------------------------------
// Kernel 2b: pure streaming masked reduction, FULLY-CONTIGUOUS sweeps.
// One wave per row. Lane owns 4 CONSECUTIVE ints -> each int4 mask load is a
// gapless 1 KB / 16-cacheline sweep (no cross-instruction line sharing); sim
// read as bf16x4 (512 B/instr). 512 cols per iter; explicit depth-2 register
// rotation keeps ~12 loads in flight per wave. No LDS, no barriers, no MFMA.
// ---------------------------------------------------------------------------
__global__ __launch_bounds__(256, 4) void reduce_rows_kernel(
    const __hip_bfloat16* __restrict__ simg,
    const int* __restrict__ pmask, const int* __restrict__ nmask,
    float* __restrict__ pos, float* __restrict__ neg, float* __restrict__ cnt,
    int passJ0, int span) {
  const int wave = threadIdx.x >> 6;
  const int lane = threadIdx.x & 63;
  const int row = blockIdx.x * 4 + wave;

  const int iters = span >> 9;  // 512 cols per iter
  const int* pm = pmask + (size_t)row * NN + passJ0;
  const int* nm = nmask + (size_t)row * NN + passJ0;
  const __hip_bfloat16* sr = simg + (size_t)row * span;
  const int l4 = lane * 4;

  // depth-2 rotation slots: per iter 4 mask int4 + 2 sim bf16x4
  int4 P0[2], P1[2], N0[2], N1[2];
  bf16x4 S0[2], S1[2];
#pragma unroll
  for (int s = 0; s < 2; ++s) {  // prologue: iters 0 and 1
    const int c0 = s * 512;
    P0[s] = *(const int4*)(pm + c0 + l4);
    P1[s] = *(const int4*)(pm + c0 + 256 + l4);
    N0[s] = *(const int4*)(nm + c0 + l4);
    N1[s] = *(const int4*)(nm + c0 + 256 + l4);
    S0[s] = *(const bf16x4*)(sr + c0 + l4);
    S1[s] = *(const bf16x4*)(sr + c0 + 256 + l4);
  }

  const int dloc = row - passJ0;  // diagonal's local col, if in this pass

  float p = 0.f, q = 0.f;
  int c = 0;
  for (int it = 0; it < iters; ++it) {
    const int s = it & 1;
    int4 cp0 = P0[s], cp1 = P1[s], cn0 = N0[s], cn1 = N1[s];
    const bf16x4 cs0 = S0[s], cs1 = S1[s];
    if (it + 2 < iters) {  // refill slot with iter it+2
      const int c0 = (it + 2) * 512;
      P0[s] = *(const int4*)(pm + c0 + l4);
      P1[s] = *(const int4*)(pm + c0 + 256 + l4);
      N0[s] = *(const int4*)(nm + c0 + l4);
      N1[s] = *(const int4*)(nm + c0 + 256 + l4);
      S0[s] = *(const bf16x4*)(sr + c0 + l4);
      S1[s] = *(const bf16x4*)(sr + c0 + 256 + l4);
    }
    // zero self-contrast: wave-uniform outer test, at most one iter per row
    const int d0 = dloc - it * 512;
    if (d0 >= 0 && d0 < 512) {
      const int z0 = d0 - l4;        // index into cp0/cn0 if in [0,4)
      const int z1 = d0 - 256 - l4;  // index into cp1/cn1 if in [0,4)
#pragma unroll
      for (int r = 0; r < 4; ++r) {
        if (z0 == r) { (&cp0.x)[r] = 0; (&cn0.x)[r] = 0; }
        if (z1 == r) { (&cp1.x)[r] = 0; (&cn1.x)[r] = 0; }
      }
    }
#pragma unroll
    for (int r = 0; r < 4; ++r) {
      const float e0 = bf2f(cs0[r]);
      const float e1 = bf2f(cs1[r]);
      const int pm0 = (&cp0.x)[r], pm1 = (&cp1.x)[r];
      p = fmaf(e0, (float)pm0, p);
      p = fmaf(e1, (float)pm1, p);
      q = fmaf(e0, (float)(&cn0.x)[r], q);
      q = fmaf(e1, (float)(&cn1.x)[r], q);
      c += pm0 + pm1;
    }
  }

  // 64-lane butterfly; all lanes end with totals
  float cf = (float)c;
#pragma unroll
  for (int m = 1; m < 64; m <<= 1) {
    p += __shfl_xor(p, m, 64);
    q += __shfl_xor(q, m, 64);
    cf += __shfl_xor(cf, m, 64);
  }
  if (lane == 0) atomicAdd(&pos[row], p);
  else if (lane == 1) atomicAdd(&neg[row], q);
  else if (lane == 2) atomicAdd(&cnt[row], cf);
}

// ---------------------------------------------------------------------------
// Kernel 3: loss = -mean(log(pos/(pos+neg)) / cnt)
// ---------------------------------------------------------------------------
__global__ __launch_bounds__(256) void finalize_kernel(
    const float* __restrict__ pos, const float* __restrict__ neg,
    const float* __restrict__ cnt, float* __restrict__ out) {
  float s = 0.f;
  for (int i = threadIdx.x; i < NN; i += 256) {
    const float p = pos[i];
    const float q = neg[i];
    s += logf(p / (p + q)) / cnt[i];
  }
#pragma unroll
  for (int m = 1; m < 64; m <<= 1) s += __shfl_xor(s, m, 64);
  __shared__ float wsum[4];
  if ((threadIdx.x & 63) == 0) wsum[threadIdx.x >> 6] = s;
  __syncthreads();
  if (threadIdx.x == 0) {
    out[0] = -(wsum[0] + wsum[1] + wsum[2] + wsum[3]) / (float)NN;
  }
}

extern "C" void kernel_launch(void* const* d_in, const int* in_sizes, int n_in,
                              void* d_out, int out_size, void* d_ws, size_t ws_size,
                              hipStream_t stream) {
  const float* features = (const float*)d_in[0];
  const int* pmask = (const int*)d_in[1];
  const int* nmask = (const int*)d_in[2];
  float* out = (float*)d_out;

  char* ws = (char*)d_ws;
  __hip_bfloat16* fn = (__hip_bfloat16*)ws;  // 2 MB
  float* pos = (float*)(ws + (size_t)NN * DD * sizeof(__hip_bfloat16));
  float* neg = pos + NN;
  float* cnt = neg + NN;
  __hip_bfloat16* simg = (__hip_bfloat16*)((char*)(cnt + NN));  // bf16 exp-sim

  // pick the widest column-pass span whose sim slice fits in the workspace
  const size_t fixed = (size_t)NN * DD * 2 + 3 * (size_t)NN * 4;
  int span = 512;
  for (int s = 8192; s >= 512; s >>= 1) {
    if (fixed + (size_t)NN * s * 2 <= ws_size) { span = s; break; }
  }
  const int npass = NN / span;

  hipMemsetAsync(pos, 0, 3 * (size_t)NN * sizeof(float), stream);
  normalize_kernel<<<NN / 4, 256, 0, stream>>>(features, fn);
  for (int ps = 0; ps < npass; ++ps) {
    sim_tile_kernel<<<dim3(span / 128, NN / 128), 256, 0, stream>>>(
        fn, simg, ps * span, span);
    reduce_rows_kernel<<<NN / 4, 256, 0, stream>>>(
        simg, pmask, nmask, pos, neg, cnt, ps * span, span);
  }
  finalize_kernel<<<1, 256, 0, stream>>>(pos, neg, cnt, out);
}